// Round 4
// baseline (1022.971 us; speedup 1.0000x reference)
//
#include <hip/hip_runtime.h>

#define S 48
#define T 16
#define NTOT (2 * S * S * S * T) // 3,538,944
#define NBLK (NTOT / 256)        // 13824 blocks, exact 1:1 thread->element

// ---- torch.gradient first derivative along an axis, unit spacing ----
// fc points AT the element (coordinate i along this axis); taps are relative.
__device__ __forceinline__ float d1(const float* __restrict__ fc, int i, int N, int stride) {
    int dl = (i > 0) ? -stride : 0;
    int dr = (i < N - 1) ? stride : 0;
    float w = (i > 0 && i < N - 1) ? 0.5f : 1.0f;
    return (fc[dr] - fc[dl]) * w;
}

// ---- composed gradient-of-gradient (what the reference's lap terms are) ----
// h = g(g(f)) closed form (N >= 5):
//  i==0   : 0.5 f0 - f1 + 0.5 f2          (rel 0,+1,+2)
//  i==1   : 0.5 f0 - 0.75 f1 + 0.25 f3    (rel -1,0,+2)
//  inner  : 0.25 (f[i-2] - 2 f[i] + f[i+2])
//  i==N-2 : 0.25 f[N-4] - 0.75 f[N-2] + 0.5 f[N-1]  (rel -2,0,+1)
//  i==N-1 : 0.5 f[N-3] - f[N-2] + 0.5 f[N-1]        (rel -2,-1,0)
__device__ __forceinline__ float d2c(const float* __restrict__ fc, int i, int N, int stride) {
    int j0, j1, j2;
    float c0, c1, c2;
    if (i == 0)          { j0 = 0;  j1 = 1;  j2 = 2; c0 = 0.5f;  c1 = -1.0f;  c2 = 0.5f;  }
    else if (i == 1)     { j0 = -1; j1 = 0;  j2 = 2; c0 = 0.5f;  c1 = -0.75f; c2 = 0.25f; }
    else if (i == N - 1) { j0 = -2; j1 = -1; j2 = 0; c0 = 0.5f;  c1 = -1.0f;  c2 = 0.5f;  }
    else if (i == N - 2) { j0 = -2; j1 = 0;  j2 = 1; c0 = 0.25f; c1 = -0.75f; c2 = 0.5f;  }
    else                 { j0 = -2; j1 = 0;  j2 = 2; c0 = 0.25f; c1 = -0.5f;  c2 = 0.25f; }
    return c0 * fc[j0 * stride] + c1 * fc[j1 * stride] + c2 * fc[j2 * stride];
}

// Element strides:
//   V/F (B,S,S,S,3,T): z: 48, x: 2304, y: 110592; channel: 16 (ch0=Vy, ch1=Vx, ch2=Vz)
//   P/Y/X/X1/C (B,S,S,S,T): z: 16, x: 768, y: 36864
// R4 design: scalar body (VGPR<=64 -> 8 waves/SIMD eligible), 1:1 grid (13824
// blocks) so the grid no longer caps occupancy at 50% like r0's 1024 blocks.
// R2/R3 lesson: vec4 t-packing needs ~152 live VGPRs -> either 2-3 waves/SIMD
// or scratch spills (553 MB of HBM writes). Occupancy quantum steps at 64/128.
__global__ __launch_bounds__(256) void fused_loss(
    const float* __restrict__ Cmat, const float* __restrict__ V,
    const float* __restrict__ P, const float* __restrict__ Xa,
    const float* __restrict__ X1a, const float* __restrict__ F,
    const float* __restrict__ Rep, const float* __restrict__ Xlast,
    const float* __restrict__ Y, float* __restrict__ ws)
{
    const float re = Rep[0];

    const int n  = blockIdx.x * 256 + threadIdx.x;  // exact: NBLK*256 == NTOT
    const int t  = n & (T - 1);
    const int sp = n >> 4;           // spatial index ((b*S+y)*S+x)*S+z
    const int z  = sp % S;
    const int r1 = sp / S;
    const int x  = r1 % S;
    const int y  = (r1 / S) % S;

    // ---- main1 / main2 / time-loss elementwise parts ----
    const float yv  = Y[n];
    const float dm1 = X1a[n] - yv;
    const float dm2 = Xa[n] - yv;
    float am1 = dm1 * dm1;
    float am2 = dm2 * dm2;
    const float yprev = (t == 0) ? Xlast[sp] : Y[n - 1];
    const float dt1 = yprev - yv;
    const float dt2 = Cmat[n] - yv;
    float at1 = dt1 * dt1;
    float at2 = dt2 * dt2;

    // ---- physics loss ----
    const float* Pc = P + n; // sp*16 + t == n
    const float dPdz = d1(Pc, z, S, 16);
    const float dPdx = d1(Pc, x, S, 768);
    const float dPdy = d1(Pc, y, S, 36864);

    const int vbase = sp * 48 + t;
    const float* Vy_c = V + vbase;       // channel 0 = Vy
    const float* Vx_c = V + vbase + 16;  // channel 1 = Vx
    const float* Vz_c = V + vbase + 32;  // channel 2 = Vz

    const float vy = *Vy_c, vx = *Vx_c, vz = *Vz_c;

    const float dVydt = d1(Vy_c, t, T, 1);
    const float dVydz = d1(Vy_c, z, S, 48);
    const float dVydx = d1(Vy_c, x, S, 2304);
    const float dVydy = d1(Vy_c, y, S, 110592);
    const float lapVy = d2c(Vy_c, z, S, 48) + d2c(Vy_c, x, S, 2304) + d2c(Vy_c, y, S, 110592);

    const float dVxdt = d1(Vx_c, t, T, 1);
    const float dVxdz = d1(Vx_c, z, S, 48);
    const float dVxdx = d1(Vx_c, x, S, 2304);
    const float dVxdy = d1(Vx_c, y, S, 110592);
    const float lapVx = d2c(Vx_c, z, S, 48) + d2c(Vx_c, x, S, 2304) + d2c(Vx_c, y, S, 110592);

    const float dVzdt = d1(Vz_c, t, T, 1);
    const float dVzdz = d1(Vz_c, z, S, 48);
    const float dVzdx = d1(Vz_c, x, S, 2304);
    const float dVzdy = d1(Vz_c, y, S, 110592);
    const float lapVz = d2c(Vz_c, z, S, 48) + d2c(Vz_c, x, S, 2304) + d2c(Vz_c, y, S, 110592);

    const float fy = F[vbase], fx = F[vbase + 16], fz = F[vbase + 32];

    const float e1 = dVydt + (vx * dVydx + vy * dVydy + vz * dVydz + dPdy) - re * lapVy + fy;
    const float e2 = dVxdt + (vx * dVxdx + vy * dVxdy + vz * dVxdz + dPdx) - re * lapVx + fx;
    const float e3 = dVzdt + (vx * dVzdx + vy * dVzdy + vz * dVzdz + dPdz) - re * lapVz + fz;
    const float e4 = dVxdx + dVydy + dVzdz;

    float aphy = e1 * e1 + e2 * e2 + e3 * e3 + e4 * e4;

    // ---- reduction: wave shuffle -> LDS -> 5 atomics per block ----
    #pragma unroll
    for (int off = 32; off > 0; off >>= 1) {
        am1  += __shfl_down(am1, off);
        am2  += __shfl_down(am2, off);
        aphy += __shfl_down(aphy, off);
        at1  += __shfl_down(at1, off);
        at2  += __shfl_down(at2, off);
    }
    __shared__ float sred[4][5];
    const int lane = threadIdx.x & 63;
    const int wv   = threadIdx.x >> 6;
    if (lane == 0) {
        sred[wv][0] = am1; sred[wv][1] = am2; sred[wv][2] = aphy;
        sred[wv][3] = at1; sred[wv][4] = at2;
    }
    __syncthreads();
    if (threadIdx.x == 0) {
        float s0 = 0.f, s1 = 0.f, s2 = 0.f, s3 = 0.f, s4 = 0.f;
        #pragma unroll
        for (int w = 0; w < 4; ++w) {
            s0 += sred[w][0]; s1 += sred[w][1]; s2 += sred[w][2];
            s3 += sred[w][3]; s4 += sred[w][4];
        }
        atomicAdd(&ws[0], s0);
        atomicAdd(&ws[1], s1);
        atomicAdd(&ws[2], s2);
        atomicAdd(&ws[3], s3);
        atomicAdd(&ws[4], s4);
    }
}

__global__ void finalize_kernel(const float* __restrict__ ws, float* __restrict__ out) {
    const float invN = 1.0f / (float)NTOT;
    const float m1  = ws[0] * invN;
    const float m2  = ws[1] * invN;
    const float phy = ws[2] * invN;
    const float t1  = ws[3] * invN;
    const float t2  = ws[4] * invN;
    out[0] = m1;
    out[1] = m2;
    out[2] = phy;
    out[3] = (t1 < t2) ? (t2 - t1) : 0.0f;
}

extern "C" void kernel_launch(void* const* d_in, const int* in_sizes, int n_in,
                              void* d_out, int out_size, void* d_ws, size_t ws_size,
                              hipStream_t stream) {
    // setup_inputs order:
    // 0 C_all, 1 V_all, 2 P_all, 3 X_all, 4 X1_all, 5 F_all, 6 Re, 7 X_last,
    // 8 Y_data, 9 maskd0, 10 maskd1, 11 maskd2
    const float* Cmat  = (const float*)d_in[0];
    const float* V     = (const float*)d_in[1];
    const float* P     = (const float*)d_in[2];
    const float* Xa    = (const float*)d_in[3];
    const float* X1a   = (const float*)d_in[4];
    const float* F     = (const float*)d_in[5];
    const float* Rep   = (const float*)d_in[6];
    const float* Xlast = (const float*)d_in[7];
    const float* Y     = (const float*)d_in[8];

    float* ws  = (float*)d_ws;
    float* out = (float*)d_out;

    hipMemsetAsync(ws, 0, 5 * sizeof(float), stream);
    fused_loss<<<NBLK, 256, 0, stream>>>(Cmat, V, P, Xa, X1a, F, Rep, Xlast, Y, ws);
    finalize_kernel<<<1, 1, 0, stream>>>(ws, out);
}

// Round 5
// 233.453 us; speedup vs baseline: 4.3819x; 4.3819x over previous
//
#include <hip/hip_runtime.h>

#define S 48
#define T 16
#define NTOT (2 * S * S * S * T) // 3,538,944
#define NBLK 2048                // = 8192 waves = full 32-waves/CU capacity at VGPR<=64
#define NSLOT 64                 // atomic slots, one cacheline (64B = 16 floats) apart

// ---- torch.gradient first derivative along an axis, unit spacing ----
__device__ __forceinline__ float d1(const float* __restrict__ fc, int i, int N, int stride) {
    int dl = (i > 0) ? -stride : 0;
    int dr = (i < N - 1) ? stride : 0;
    float w = (i > 0 && i < N - 1) ? 0.5f : 1.0f;
    return (fc[dr] - fc[dl]) * w;
}

// ---- composed gradient-of-gradient (the reference's lap terms) ----
//  i==0   : 0.5 f0 - f1 + 0.5 f2
//  i==1   : 0.5 f0 - 0.75 f1 + 0.25 f3
//  inner  : 0.25 (f[i-2] - 2 f[i] + f[i+2])
//  i==N-2 : 0.25 f[N-4] - 0.75 f[N-2] + 0.5 f[N-1]
//  i==N-1 : 0.5 f[N-3] - f[N-2] + 0.5 f[N-1]
__device__ __forceinline__ float d2c(const float* __restrict__ fc, int i, int N, int stride) {
    int j0, j1, j2;
    float c0, c1, c2;
    if (i == 0)          { j0 = 0;  j1 = 1;  j2 = 2; c0 = 0.5f;  c1 = -1.0f;  c2 = 0.5f;  }
    else if (i == 1)     { j0 = -1; j1 = 0;  j2 = 2; c0 = 0.5f;  c1 = -0.75f; c2 = 0.25f; }
    else if (i == N - 1) { j0 = -2; j1 = -1; j2 = 0; c0 = 0.5f;  c1 = -1.0f;  c2 = 0.5f;  }
    else if (i == N - 2) { j0 = -2; j1 = 0;  j2 = 1; c0 = 0.25f; c1 = -0.75f; c2 = 0.5f;  }
    else                 { j0 = -2; j1 = 0;  j2 = 2; c0 = 0.25f; c1 = -0.5f;  c2 = 0.25f; }
    return c0 * fc[j0 * stride] + c1 * fc[j1 * stride] + c2 * fc[j2 * stride];
}

// Element strides:
//   V/F (B,S,S,S,3,T): z: 48, x: 2304, y: 110592; channel: 16 (ch0=Vy, ch1=Vx, ch2=Vz)
//   P/Y/X/X1/C (B,S,S,S,T): z: 16, x: 768, y: 36864
//
// R4 post-mortem: all blocks atomically adding to the SAME 5 floats serialized
// block retirement (one cacheline ping-ponging across 8 non-coherent XCD L2s;
// occupancy pinned at exactly 1/4 = wave0-only resident). Fix: 64 cacheline-
// spaced accumulator slots (blockIdx&63) + grid-stride with 2048 blocks.
__global__ __launch_bounds__(256) void fused_loss(
    const float* __restrict__ Cmat, const float* __restrict__ V,
    const float* __restrict__ P, const float* __restrict__ Xa,
    const float* __restrict__ X1a, const float* __restrict__ F,
    const float* __restrict__ Rep, const float* __restrict__ Xlast,
    const float* __restrict__ Y, float* __restrict__ ws)
{
    const float re = Rep[0];
    float am1 = 0.f, am2 = 0.f, aphy = 0.f, at1 = 0.f, at2 = 0.f;

    const int gstride = NBLK * 256;
    for (int n = blockIdx.x * 256 + threadIdx.x; n < NTOT; n += gstride) {
        const int t  = n & (T - 1);
        const int sp = n >> 4;           // spatial index ((b*S+y)*S+x)*S+z
        const int z  = sp % S;
        const int r1 = sp / S;
        const int x  = r1 % S;
        const int y  = (r1 / S) % S;

        // ---- main1 / main2 / time-loss elementwise parts ----
        const float yv  = Y[n];
        const float dm1 = X1a[n] - yv;
        const float dm2 = Xa[n] - yv;
        am1 += dm1 * dm1;
        am2 += dm2 * dm2;
        const float yprev = (t == 0) ? Xlast[sp] : Y[n - 1];
        const float dt1 = yprev - yv;
        const float dt2 = Cmat[n] - yv;
        at1 += dt1 * dt1;
        at2 += dt2 * dt2;

        // ---- physics loss ----
        const float* Pc = P + n; // sp*16 + t == n
        const float dPdz = d1(Pc, z, S, 16);
        const float dPdx = d1(Pc, x, S, 768);
        const float dPdy = d1(Pc, y, S, 36864);

        const int vbase = sp * 48 + t;
        const float* Vy_c = V + vbase;       // channel 0 = Vy
        const float* Vx_c = V + vbase + 16;  // channel 1 = Vx
        const float* Vz_c = V + vbase + 32;  // channel 2 = Vz

        const float vy = *Vy_c, vx = *Vx_c, vz = *Vz_c;

        const float dVydt = d1(Vy_c, t, T, 1);
        const float dVydz = d1(Vy_c, z, S, 48);
        const float dVydx = d1(Vy_c, x, S, 2304);
        const float dVydy = d1(Vy_c, y, S, 110592);
        const float lapVy = d2c(Vy_c, z, S, 48) + d2c(Vy_c, x, S, 2304) + d2c(Vy_c, y, S, 110592);

        const float dVxdt = d1(Vx_c, t, T, 1);
        const float dVxdz = d1(Vx_c, z, S, 48);
        const float dVxdx = d1(Vx_c, x, S, 2304);
        const float dVxdy = d1(Vx_c, y, S, 110592);
        const float lapVx = d2c(Vx_c, z, S, 48) + d2c(Vx_c, x, S, 2304) + d2c(Vx_c, y, S, 110592);

        const float dVzdt = d1(Vz_c, t, T, 1);
        const float dVzdz = d1(Vz_c, z, S, 48);
        const float dVzdx = d1(Vz_c, x, S, 2304);
        const float dVzdy = d1(Vz_c, y, S, 110592);
        const float lapVz = d2c(Vz_c, z, S, 48) + d2c(Vz_c, x, S, 2304) + d2c(Vz_c, y, S, 110592);

        const float fy = F[vbase], fx = F[vbase + 16], fz = F[vbase + 32];

        const float e1 = dVydt + (vx * dVydx + vy * dVydy + vz * dVydz + dPdy) - re * lapVy + fy;
        const float e2 = dVxdt + (vx * dVxdx + vy * dVxdy + vz * dVxdz + dPdx) - re * lapVx + fx;
        const float e3 = dVzdt + (vx * dVzdx + vy * dVzdy + vz * dVzdz + dPdz) - re * lapVz + fz;
        const float e4 = dVxdx + dVydy + dVzdz;

        aphy += e1 * e1 + e2 * e2 + e3 * e3 + e4 * e4;
    }

    // ---- reduction: wave shuffle -> LDS -> 5 atomics to a cacheline-spread slot ----
    #pragma unroll
    for (int off = 32; off > 0; off >>= 1) {
        am1  += __shfl_down(am1, off);
        am2  += __shfl_down(am2, off);
        aphy += __shfl_down(aphy, off);
        at1  += __shfl_down(at1, off);
        at2  += __shfl_down(at2, off);
    }
    __shared__ float sred[4][5];
    const int lane = threadIdx.x & 63;
    const int wv   = threadIdx.x >> 6;
    if (lane == 0) {
        sred[wv][0] = am1; sred[wv][1] = am2; sred[wv][2] = aphy;
        sred[wv][3] = at1; sred[wv][4] = at2;
    }
    __syncthreads();
    if (threadIdx.x == 0) {
        float s0 = 0.f, s1 = 0.f, s2 = 0.f, s3 = 0.f, s4 = 0.f;
        #pragma unroll
        for (int w = 0; w < 4; ++w) {
            s0 += sred[w][0]; s1 += sred[w][1]; s2 += sred[w][2];
            s3 += sred[w][3]; s4 += sred[w][4];
        }
        float* slot = ws + (blockIdx.x & (NSLOT - 1)) * 16; // 64B apart
        atomicAdd(&slot[0], s0);
        atomicAdd(&slot[1], s1);
        atomicAdd(&slot[2], s2);
        atomicAdd(&slot[3], s3);
        atomicAdd(&slot[4], s4);
    }
}

// 64 threads: lane l sums slot l, then wave-shuffle combine.
__global__ void finalize_kernel(const float* __restrict__ ws, float* __restrict__ out) {
    const int l = threadIdx.x; // 0..63
    float s0 = ws[l * 16 + 0];
    float s1 = ws[l * 16 + 1];
    float s2 = ws[l * 16 + 2];
    float s3 = ws[l * 16 + 3];
    float s4 = ws[l * 16 + 4];
    #pragma unroll
    for (int off = 32; off > 0; off >>= 1) {
        s0 += __shfl_down(s0, off);
        s1 += __shfl_down(s1, off);
        s2 += __shfl_down(s2, off);
        s3 += __shfl_down(s3, off);
        s4 += __shfl_down(s4, off);
    }
    if (l == 0) {
        const float invN = 1.0f / (float)NTOT;
        const float m1  = s0 * invN;
        const float m2  = s1 * invN;
        const float phy = s2 * invN;
        const float t1  = s3 * invN;
        const float t2  = s4 * invN;
        out[0] = m1;
        out[1] = m2;
        out[2] = phy;
        out[3] = (t1 < t2) ? (t2 - t1) : 0.0f;
    }
}

extern "C" void kernel_launch(void* const* d_in, const int* in_sizes, int n_in,
                              void* d_out, int out_size, void* d_ws, size_t ws_size,
                              hipStream_t stream) {
    // setup_inputs order:
    // 0 C_all, 1 V_all, 2 P_all, 3 X_all, 4 X1_all, 5 F_all, 6 Re, 7 X_last,
    // 8 Y_data, 9 maskd0, 10 maskd1, 11 maskd2
    const float* Cmat  = (const float*)d_in[0];
    const float* V     = (const float*)d_in[1];
    const float* P     = (const float*)d_in[2];
    const float* Xa    = (const float*)d_in[3];
    const float* X1a   = (const float*)d_in[4];
    const float* F     = (const float*)d_in[5];
    const float* Rep   = (const float*)d_in[6];
    const float* Xlast = (const float*)d_in[7];
    const float* Y     = (const float*)d_in[8];

    float* ws  = (float*)d_ws;
    float* out = (float*)d_out;

    hipMemsetAsync(ws, 0, NSLOT * 16 * sizeof(float), stream); // 4 KB of slots
    fused_loss<<<NBLK, 256, 0, stream>>>(Cmat, V, P, Xa, X1a, F, Rep, Xlast, Y, ws);
    finalize_kernel<<<1, 64, 0, stream>>>(ws, out);
}